// Round 1
// baseline (19476.544 us; speedup 1.0000x reference)
//
#include <hip/hip_runtime.h>
#include <math.h>

#define THR  0.05f
#define BETA 0.9181805491303656f

#define B_SZ 64
#define T_STEPS 25

__device__ __forceinline__ float sigf(float x) { return 1.0f / (1.0f + expf(-x)); }

// ---------------------------------------------------------------------------
// Fused ConvLSTM step: gates = conv3x3(cat(x, mem_in)) + bias (SAME pad),
// then syn' = sig(f)*syn + sig(i)*tanh(g);  mem' = sig(o)*tanh(syn').
// One thread per output element (b, c, h, w). mem double-buffered, syn in-place.
// ---------------------------------------------------------------------------
template<int Cin, int Ch, int H, int W>
__global__ __launch_bounds__(256) void convlstm_kernel(
    const float* __restrict__ xin,    // (B, Cin, H, W)
    const float* __restrict__ memin,  // (B, Ch, H, W)
    const float* __restrict__ synin,  // (B, Ch, H, W)
    float* __restrict__ synout,       // (B, Ch, H, W)  (may alias synin)
    float* __restrict__ memout,       // (B, Ch, H, W)
    const float* __restrict__ wt,     // (4*Ch, Cin+Ch, 3, 3)
    const float* __restrict__ bias)   // (4*Ch)
{
    constexpr int CIN = Cin + Ch;
    const int idx = blockIdx.x * blockDim.x + threadIdx.x;
    const int w = idx % W;
    const int h = (idx / W) % H;
    const int c = (idx / (W * H)) % Ch;
    const int b = idx / (W * H * Ch);

    float gi = bias[c];
    float gf = bias[c + Ch];
    float gg = bias[c + 2 * Ch];
    float go = bias[c + 3 * Ch];

    const float* w_i = wt + (size_t)(0 * Ch + c) * CIN * 9;
    const float* w_f = wt + (size_t)(1 * Ch + c) * CIN * 9;
    const float* w_g = wt + (size_t)(2 * Ch + c) * CIN * 9;
    const float* w_o = wt + (size_t)(3 * Ch + c) * CIN * 9;

    for (int ci = 0; ci < CIN; ++ci) {
        const float* src = (ci < Cin)
            ? (xin + ((size_t)b * Cin + ci) * (H * W))
            : (memin + ((size_t)b * Ch + (ci - Cin)) * (H * W));
        const int tap0 = ci * 9;
        #pragma unroll
        for (int dy = 0; dy < 3; ++dy) {
            const int y = h + dy - 1;
            if (y < 0 || y >= H) continue;
            #pragma unroll
            for (int dx = 0; dx < 3; ++dx) {
                const int xx = w + dx - 1;
                if (xx < 0 || xx >= W) continue;
                const float v = src[y * W + xx];
                const int tap = tap0 + dy * 3 + dx;
                gi = fmaf(v, w_i[tap], gi);
                gf = fmaf(v, w_f[tap], gf);
                gg = fmaf(v, w_g[tap], gg);
                go = fmaf(v, w_o[tap], go);
            }
        }
    }

    const float syn = sigf(gf) * synin[idx] + sigf(gi) * tanhf(gg);
    const float mem = sigf(go) * tanhf(syn);
    synout[idx] = syn;
    memout[idx] = mem;
}

// ---------------------------------------------------------------------------
// spk = heaviside(maxpool2x2(mem) - THR). One thread per pooled element.
// ---------------------------------------------------------------------------
template<int H, int W>
__global__ __launch_bounds__(256) void poolspike_kernel(
    const float* __restrict__ mem,  // (B, Ch, H, W)
    float* __restrict__ spk)        // (B, Ch, H/2, W/2)
{
    constexpr int PW = W / 2;
    constexpr int PH = H / 2;
    const int idx = blockIdx.x * blockDim.x + threadIdx.x;
    const int pw = idx % PW;
    const int ph = (idx / PW) % PH;
    const int bc = idx / (PW * PH);
    const float* m = mem + (size_t)bc * H * W;
    const int y = ph * 2, x = pw * 2;
    const float v0 = m[y * W + x];
    const float v1 = m[y * W + x + 1];
    const float v2 = m[(y + 1) * W + x];
    const float v3 = m[(y + 1) * W + x + 1];
    const float mx = fmaxf(fmaxf(v0, v1), fmaxf(v2, v3));
    spk[idx] = ((mx - THR) > 0.0f) ? 1.0f : 0.0f;
}

// ---------------------------------------------------------------------------
// cur4 = spk3 @ fc1_w.T + fc1_b; Leaky(mem4). One wave per (b, o) output.
// ---------------------------------------------------------------------------
__global__ __launch_bounds__(256) void fc1_kernel(
    const float* __restrict__ spk3,  // (B, 2048)
    const float* __restrict__ wt,    // (512, 2048)
    const float* __restrict__ bias,  // (512)
    float* __restrict__ mem4,        // (B, 512)
    float* __restrict__ spk4)        // (B, 512)
{
    const int wid = (blockIdx.x * blockDim.x + threadIdx.x) >> 6;
    const int lane = threadIdx.x & 63;
    const int o = wid & 511;
    const int b = wid >> 9;
    const float* wr = wt + (size_t)o * 2048;
    const float* sr = spk3 + (size_t)b * 2048;
    float acc = 0.0f;
    #pragma unroll
    for (int i = 0; i < 32; ++i)
        acc = fmaf(sr[lane + i * 64], wr[lane + i * 64], acc);
    #pragma unroll
    for (int off = 32; off; off >>= 1)
        acc += __shfl_down(acc, off, 64);
    if (lane == 0) {
        const float cur = acc + bias[o];
        const int i4 = b * 512 + o;
        float m = mem4[i4];
        const float reset = (m > THR) ? 1.0f : 0.0f;
        m = BETA * m + cur - reset * THR;
        spk4[i4] = ((m - THR) > 0.0f) ? 1.0f : 0.0f;
        mem4[i4] = m;
    }
}

// ---------------------------------------------------------------------------
// cur5 = spk4 @ fc2_w.T + fc2_b; Leaky(mem5); writes spk_rec[t], mem_rec[t].
// One wave per (b, o), 128 waves total.
// ---------------------------------------------------------------------------
__global__ __launch_bounds__(256) void fc2_kernel(
    const float* __restrict__ spk4,   // (B, 512)
    const float* __restrict__ wt,     // (2, 512)
    const float* __restrict__ bias,   // (2)
    float* __restrict__ mem5,         // (B, 2)
    float* __restrict__ out_spk,      // (B, 2) slice of d_out
    float* __restrict__ out_mem)      // (B, 2) slice of d_out
{
    const int wid = (blockIdx.x * blockDim.x + threadIdx.x) >> 6;
    const int lane = threadIdx.x & 63;
    if (wid >= 2 * B_SZ) return;
    const int o = wid & 1;
    const int b = wid >> 1;
    const float* wr = wt + (size_t)o * 512;
    const float* sr = spk4 + (size_t)b * 512;
    float acc = 0.0f;
    #pragma unroll
    for (int i = 0; i < 8; ++i)
        acc = fmaf(sr[lane + i * 64], wr[lane + i * 64], acc);
    #pragma unroll
    for (int off = 32; off; off >>= 1)
        acc += __shfl_down(acc, off, 64);
    if (lane == 0) {
        const float cur = acc + bias[o];
        const int i5 = b * 2 + o;
        float m = mem5[i5];
        const float reset = (m > THR) ? 1.0f : 0.0f;
        m = BETA * m + cur - reset * THR;
        out_spk[i5] = ((m - THR) > 0.0f) ? 1.0f : 0.0f;
        out_mem[i5] = m;
        mem5[i5] = m;
    }
}

extern "C" void kernel_launch(void* const* d_in, const int* in_sizes, int n_in,
                              void* d_out, int out_size, void* d_ws, size_t ws_size,
                              hipStream_t stream) {
    (void)in_sizes; (void)n_in; (void)out_size; (void)ws_size;

    const float* x     = (const float*)d_in[0];   // (25, 64, 16, 128)
    const float* w1    = (const float*)d_in[1];   // (64, 17, 3, 3)
    const float* b1    = (const float*)d_in[2];   // (64)
    const float* w2    = (const float*)d_in[3];   // (128, 48, 3, 3)
    const float* b2    = (const float*)d_in[4];   // (128)
    const float* w3    = (const float*)d_in[5];   // (256, 96, 3, 3)
    const float* b3    = (const float*)d_in[6];   // (256)
    const float* fc1w  = (const float*)d_in[7];   // (512, 2048)
    const float* fc1b  = (const float*)d_in[8];   // (512)
    const float* fc2w  = (const float*)d_in[9];   // (2, 512)
    const float* fc2b  = (const float*)d_in[10];  // (2)

    float* out = (float*)d_out;                   // spk_rec (25,64,2) ++ mem_rec (25,64,2)
    float* ws = (float*)d_ws;

    // workspace layout (floats)
    const size_t N1 = (size_t)B_SZ * 16 * 16 * 128;  // 2,097,152
    const size_t N2 = (size_t)B_SZ * 32 * 8 * 64;    // 1,048,576
    const size_t N3 = (size_t)B_SZ * 64 * 4 * 32;    //   524,288
    const size_t P1 = N1 / 4, P2 = N2 / 4, P3 = N3 / 4;

    size_t off = 0;
    float* syn1  = ws + off; off += N1;
    float* mem1a = ws + off; off += N1;
    float* mem1b = ws + off; off += N1;
    float* syn2  = ws + off; off += N2;
    float* mem2a = ws + off; off += N2;
    float* mem2b = ws + off; off += N2;
    float* syn3  = ws + off; off += N3;
    float* mem3a = ws + off; off += N3;
    float* mem3b = ws + off; off += N3;
    float* mem4  = ws + off; off += (size_t)B_SZ * 512;
    float* mem5  = ws + off; off += (size_t)B_SZ * 2;
    const size_t zero_elems = off;                 // states must start at 0
    float* spk1 = ws + off; off += P1;
    float* spk2 = ws + off; off += P2;
    float* spk3 = ws + off; off += P3;
    float* spk4 = ws + off; off += (size_t)B_SZ * 512;

    hipMemsetAsync(d_ws, 0, zero_elems * sizeof(float), stream);

    float* m1r = mem1a; float* m1w = mem1b;
    float* m2r = mem2a; float* m2w = mem2b;
    float* m3r = mem3a; float* m3w = mem3b;

    for (int t = 0; t < T_STEPS; ++t) {
        const float* xt = x + (size_t)t * B_SZ * 16 * 128;

        convlstm_kernel<1, 16, 16, 128><<<N1 / 256, 256, 0, stream>>>(
            xt, m1r, syn1, syn1, m1w, w1, b1);
        poolspike_kernel<16, 128><<<P1 / 256, 256, 0, stream>>>(m1w, spk1);

        convlstm_kernel<16, 32, 8, 64><<<N2 / 256, 256, 0, stream>>>(
            spk1, m2r, syn2, syn2, m2w, w2, b2);
        poolspike_kernel<8, 64><<<P2 / 256, 256, 0, stream>>>(m2w, spk2);

        convlstm_kernel<32, 64, 4, 32><<<N3 / 256, 256, 0, stream>>>(
            spk2, m3r, syn3, syn3, m3w, w3, b3);
        poolspike_kernel<4, 32><<<P3 / 256, 256, 0, stream>>>(m3w, spk3);

        fc1_kernel<<<(B_SZ * 512) / 4, 256, 0, stream>>>(spk3, fc1w, fc1b, mem4, spk4);
        fc2_kernel<<<(2 * B_SZ + 3) / 4, 256, 0, stream>>>(
            spk4, fc2w, fc2b, mem5, out + (size_t)t * 2 * B_SZ,
            out + 3200 + (size_t)t * 2 * B_SZ);

        float* tmp;
        tmp = m1r; m1r = m1w; m1w = tmp;
        tmp = m2r; m2r = m2w; m2w = tmp;
        tmp = m3r; m3r = m3w; m3w = tmp;
    }
}

// Round 2
// 5324.512 us; speedup vs baseline: 3.6579x; 3.6579x over previous
//
#include <hip/hip_runtime.h>
#include <math.h>

#define THR  0.05f
#define BETA 0.9181805491303656f
#define B_SZ 64
#define T_STEPS 25

__device__ __forceinline__ float sigf(float x) { return 1.0f / (1.0f + __expf(-x)); }
__device__ __forceinline__ float tanh_fast(float x) {
    const float xc = fminf(fmaxf(x, -10.0f), 10.0f);
    const float e = __expf(2.0f * xc);
    return (e - 1.0f) / (e + 1.0f);
}

// ---------------------------------------------------------------------------
// Repack conv weights from (4*Ch, CIN, 3, 3) [OIHW] to [ci*9+tap][gate][c]
// so compute lanes (c fastest) load coalesced & taps are contiguous.
// ---------------------------------------------------------------------------
__global__ __launch_bounds__(256) void repack_kernel(
    const float* __restrict__ wt, float* __restrict__ wr, int Ch, int CIN)
{
    const int n = 4 * Ch * CIN * 9;
    for (int i = blockIdx.x * 256 + threadIdx.x; i < n; i += gridDim.x * 256) {
        const int c  = i % Ch;
        const int g  = (i / Ch) % 4;
        const int ct = i / (4 * Ch);      // ci*9 + tap
        wr[i] = wt[(size_t)(g * Ch + c) * (CIN * 9) + ct];
    }
}

// ---------------------------------------------------------------------------
// Fused ConvLSTM step. Input tile (cat(x|pooled-spike, mem)) staged in LDS
// with zero-padded halo. Thread computes P=8 consecutive pixels for one c:
// per ci: 9 float4/float2 LDS strip reads + 36 coalesced weight loads + 288 FMA.
// ---------------------------------------------------------------------------
template<int Cin, int Ch, int H, int W, int R, int CSPLIT, bool POOL_IN>
__global__ __launch_bounds__(256) void conv_lstm(
    const float* __restrict__ xin,    // raw (B,Cin,H,W) or prev mem (B,Cin,2H,2W) if POOL_IN
    const float* __restrict__ memin,  // (B,Ch,H,W)
    const float* __restrict__ synin,
    float* __restrict__ synout,
    float* __restrict__ memout,
    const float* __restrict__ wr,     // repacked [CIN*9][4][Ch]
    const float* __restrict__ bias)   // (4*Ch)
{
    constexpr int P = 8;
    constexpr int CIN = Cin + Ch;
    constexpr int SW = W + 4;          // row stride (16B aligned), cols: 0 = x=-1 pad
    constexpr int R2 = R + 2;
    constexpr int ChB = Ch / CSPLIT;
    constexpr int NREST = 256 / ChB;
    constexpr int COMBOS = R * (W / P);
    static_assert(256 % ChB == 0, "");
    static_assert(W % P == 0, "");

    __shared__ float tile[CIN * R2 * SW];

    const int tid = threadIdx.x;
    const int bid = blockIdx.x;
    const int cs = bid % CSPLIT;
    const int rs = (bid / CSPLIT) % (H / R);
    const int b  = bid / (CSPLIT * (H / R));
    const int r0 = rs * R;
    const int c0 = cs * ChB;

    for (int i = tid; i < CIN * R2 * SW; i += 256) tile[i] = 0.0f;
    __syncthreads();

    for (int i = tid; i < CIN * R2 * W; i += 256) {
        const int wx = i % W;
        const int ry = (i / W) % R2;
        const int ci = i / (W * R2);
        const int gy = r0 + ry - 1;
        if (gy < 0 || gy >= H) continue;
        float v;
        if (POOL_IN && ci < Cin) {
            const float* mp = xin + (((size_t)b * Cin + ci) * (2 * H) + 2 * gy) * (2 * W) + 2 * wx;
            const float mx = fmaxf(fmaxf(mp[0], mp[1]), fmaxf(mp[2 * W], mp[2 * W + 1]));
            v = (mx - THR) > 0.0f ? 1.0f : 0.0f;
        } else if (ci < Cin) {
            v = xin[(((size_t)b * Cin + ci) * H + gy) * W + wx];
        } else {
            v = memin[(((size_t)b * Ch + (ci - Cin)) * H + gy) * W + wx];
        }
        tile[(ci * R2 + ry) * SW + wx + 1] = v;
    }
    __syncthreads();

    const int c_sub = tid % ChB;
    const int rest  = tid / ChB;
    const int c = c0 + c_sub;

    const float b_i = bias[c];
    const float b_f = bias[c + Ch];
    const float b_g = bias[c + 2 * Ch];
    const float b_o = bias[c + 3 * Ch];

    for (int task = rest; task < COMBOS; task += NREST) {
        const int wg = task % (W / P);
        const int rl = task / (W / P);
        const int x0 = wg * P;
        const int gr = r0 + rl;

        float gi[P], gf[P], gg[P], go[P];
        #pragma unroll
        for (int p = 0; p < P; ++p) { gi[p] = b_i; gf[p] = b_f; gg[p] = b_g; go[p] = b_o; }

        #pragma unroll 1
        for (int ci = 0; ci < CIN; ++ci) {
            float s[3][P + 2];
            #pragma unroll
            for (int dy = 0; dy < 3; ++dy) {
                const float* rp = &tile[(ci * R2 + rl + dy) * SW + x0];
                const float4 a  = *(const float4*)rp;
                const float4 bq = *(const float4*)(rp + 4);
                const float2 cq = *(const float2*)(rp + 8);
                s[dy][0] = a.x;  s[dy][1] = a.y;  s[dy][2] = a.z;  s[dy][3] = a.w;
                s[dy][4] = bq.x; s[dy][5] = bq.y; s[dy][6] = bq.z; s[dy][7] = bq.w;
                s[dy][8] = cq.x; s[dy][9] = cq.y;
            }
            const float* wp = wr + (size_t)ci * 36 * Ch + c;
            #pragma unroll
            for (int tap = 0; tap < 9; ++tap) {
                const float wi = wp[(tap * 4 + 0) * Ch];
                const float wf = wp[(tap * 4 + 1) * Ch];
                const float wg_ = wp[(tap * 4 + 2) * Ch];
                const float wo = wp[(tap * 4 + 3) * Ch];
                const int dy = tap / 3, dx = tap % 3;
                #pragma unroll
                for (int p = 0; p < P; ++p) {
                    const float v = s[dy][p + dx];
                    gi[p] = fmaf(v, wi, gi[p]);
                    gf[p] = fmaf(v, wf, gf[p]);
                    gg[p] = fmaf(v, wg_, gg[p]);
                    go[p] = fmaf(v, wo, go[p]);
                }
            }
        }

        const size_t base = (((size_t)b * Ch + c) * H + gr) * W + x0;
        #pragma unroll
        for (int p = 0; p < P; ++p) {
            const float syn = sigf(gf[p]) * synin[base + p] + sigf(gi[p]) * tanh_fast(gg[p]);
            const float mem = sigf(go[p]) * tanh_fast(syn);
            synout[base + p] = syn;
            memout[base + p] = mem;
        }
    }
}

// ---------------------------------------------------------------------------
// spk = heaviside(maxpool2x2(mem) - THR). One thread per pooled element.
// ---------------------------------------------------------------------------
template<int H, int W>
__global__ __launch_bounds__(256) void poolspike_kernel(
    const float* __restrict__ mem, float* __restrict__ spk)
{
    constexpr int PW = W / 2;
    constexpr int PH = H / 2;
    const int idx = blockIdx.x * blockDim.x + threadIdx.x;
    const int pw = idx % PW;
    const int ph = (idx / PW) % PH;
    const int bc = idx / (PW * PH);
    const float* m = mem + (size_t)bc * H * W;
    const int y = ph * 2, x = pw * 2;
    const float mx = fmaxf(fmaxf(m[y * W + x], m[y * W + x + 1]),
                           fmaxf(m[(y + 1) * W + x], m[(y + 1) * W + x + 1]));
    spk[idx] = ((mx - THR) > 0.0f) ? 1.0f : 0.0f;
}

// ---------------------------------------------------------------------------
// cur4 = spk3 @ fc1_w.T + fc1_b; Leaky(mem4). Wave computes 8 outputs (float4 K).
// ---------------------------------------------------------------------------
__global__ __launch_bounds__(256) void fc1_kernel(
    const float* __restrict__ spk3,  // (B, 2048)
    const float* __restrict__ wt,    // (512, 2048)
    const float* __restrict__ bias,
    float* __restrict__ mem4,        // (B, 512)
    float* __restrict__ spk4)        // (B, 512)
{
    const int wid = (blockIdx.x * 256 + threadIdx.x) >> 6;
    const int lane = threadIdx.x & 63;
    const int og = wid & 63;
    const int b = wid >> 6;
    const int o0 = og * 8;
    const float* sr = spk3 + (size_t)b * 2048;

    float acc[8] = {0, 0, 0, 0, 0, 0, 0, 0};
    for (int it = 0; it < 8; ++it) {
        const int k = (it * 64 + lane) * 4;
        const float4 sv = *(const float4*)(sr + k);
        #pragma unroll
        for (int j = 0; j < 8; ++j) {
            const float4 wv = *(const float4*)(wt + (size_t)(o0 + j) * 2048 + k);
            acc[j] = fmaf(sv.x, wv.x, acc[j]);
            acc[j] = fmaf(sv.y, wv.y, acc[j]);
            acc[j] = fmaf(sv.z, wv.z, acc[j]);
            acc[j] = fmaf(sv.w, wv.w, acc[j]);
        }
    }
    float mine = 0.0f;
    #pragma unroll
    for (int j = 0; j < 8; ++j) {
        float a = acc[j];
        #pragma unroll
        for (int off = 32; off; off >>= 1) a += __shfl_xor(a, off, 64);
        if (lane == j) mine = a;
    }
    if (lane < 8) {
        const int o = o0 + lane;
        const float cur = mine + bias[o];
        const int i4 = b * 512 + o;
        float m = mem4[i4];
        const float reset = (m > THR) ? 1.0f : 0.0f;
        m = BETA * m + cur - reset * THR;
        spk4[i4] = ((m - THR) > 0.0f) ? 1.0f : 0.0f;
        mem4[i4] = m;
    }
}

// ---------------------------------------------------------------------------
// cur5 = spk4 @ fc2_w.T + fc2_b; Leaky(mem5); writes spk_rec[t], mem_rec[t].
// ---------------------------------------------------------------------------
__global__ __launch_bounds__(256) void fc2_kernel(
    const float* __restrict__ spk4,
    const float* __restrict__ wt,
    const float* __restrict__ bias,
    float* __restrict__ mem5,
    float* __restrict__ out_spk,
    float* __restrict__ out_mem)
{
    const int wid = (blockIdx.x * 256 + threadIdx.x) >> 6;
    const int lane = threadIdx.x & 63;
    if (wid >= 2 * B_SZ) return;
    const int o = wid & 1;
    const int b = wid >> 1;
    const float* wr = wt + (size_t)o * 512;
    const float* sr = spk4 + (size_t)b * 512;
    float acc = 0.0f;
    #pragma unroll
    for (int i = 0; i < 8; ++i)
        acc = fmaf(sr[lane + i * 64], wr[lane + i * 64], acc);
    #pragma unroll
    for (int off = 32; off; off >>= 1) acc += __shfl_down(acc, off, 64);
    if (lane == 0) {
        const float cur = acc + bias[o];
        const int i5 = b * 2 + o;
        float m = mem5[i5];
        const float reset = (m > THR) ? 1.0f : 0.0f;
        m = BETA * m + cur - reset * THR;
        out_spk[i5] = ((m - THR) > 0.0f) ? 1.0f : 0.0f;
        out_mem[i5] = m;
        mem5[i5] = m;
    }
}

extern "C" void kernel_launch(void* const* d_in, const int* in_sizes, int n_in,
                              void* d_out, int out_size, void* d_ws, size_t ws_size,
                              hipStream_t stream) {
    (void)in_sizes; (void)n_in; (void)out_size; (void)ws_size;

    const float* x    = (const float*)d_in[0];
    const float* w1   = (const float*)d_in[1];
    const float* b1   = (const float*)d_in[2];
    const float* w2   = (const float*)d_in[3];
    const float* b2   = (const float*)d_in[4];
    const float* w3   = (const float*)d_in[5];
    const float* b3   = (const float*)d_in[6];
    const float* fc1w = (const float*)d_in[7];
    const float* fc1b = (const float*)d_in[8];
    const float* fc2w = (const float*)d_in[9];
    const float* fc2b = (const float*)d_in[10];

    float* out = (float*)d_out;
    float* ws = (float*)d_ws;

    const size_t N1 = (size_t)B_SZ * 16 * 16 * 128;
    const size_t N2 = (size_t)B_SZ * 32 * 8 * 64;
    const size_t N3 = (size_t)B_SZ * 64 * 4 * 32;

    size_t off = 0;
    float* syn1  = ws + off; off += N1;
    float* mem1a = ws + off; off += N1;
    float* mem1b = ws + off; off += N1;
    float* syn2  = ws + off; off += N2;
    float* mem2a = ws + off; off += N2;
    float* mem2b = ws + off; off += N2;
    float* syn3  = ws + off; off += N3;
    float* mem3a = ws + off; off += N3;
    float* mem3b = ws + off; off += N3;
    float* mem4  = ws + off; off += (size_t)B_SZ * 512;
    float* mem5  = ws + off; off += (size_t)B_SZ * 2;
    const size_t zero_elems = off;
    float* spk3 = ws + off; off += N3 / 4;
    float* spk4 = ws + off; off += (size_t)B_SZ * 512;
    float* wr1  = ws + off; off += (size_t)64 * 17 * 9;
    float* wr2  = ws + off; off += (size_t)128 * 48 * 9;
    float* wr3  = ws + off; off += (size_t)256 * 96 * 9;

    hipMemsetAsync(d_ws, 0, zero_elems * sizeof(float), stream);

    repack_kernel<<<64, 256, 0, stream>>>(w1, wr1, 16, 17);
    repack_kernel<<<64, 256, 0, stream>>>(w2, wr2, 32, 48);
    repack_kernel<<<64, 256, 0, stream>>>(w3, wr3, 64, 96);

    float* m1r = mem1a; float* m1w = mem1b;
    float* m2r = mem2a; float* m2w = mem2b;
    float* m3r = mem3a; float* m3w = mem3b;

    for (int t = 0; t < T_STEPS; ++t) {
        const float* xt = x + (size_t)t * B_SZ * 16 * 128;

        // L1: grid = B * (H/R) = 64*8 = 512
        conv_lstm<1, 16, 16, 128, 2, 1, false><<<512, 256, 0, stream>>>(
            xt, m1r, syn1, syn1, m1w, wr1, b1);
        // L2: grid = B * (H/R) * CSPLIT = 64*4*2 = 512
        conv_lstm<16, 32, 8, 64, 2, 2, true><<<512, 256, 0, stream>>>(
            m1w, m2r, syn2, syn2, m2w, wr2, b2);
        // L3: grid = 64*2*2 = 256
        conv_lstm<32, 64, 4, 32, 2, 2, true><<<256, 256, 0, stream>>>(
            m2w, m3r, syn3, syn3, m3w, wr3, b3);

        poolspike_kernel<4, 32><<<(N3 / 4) / 256, 256, 0, stream>>>(m3w, spk3);

        fc1_kernel<<<1024, 256, 0, stream>>>(spk3, fc1w, fc1b, mem4, spk4);
        fc2_kernel<<<32, 256, 0, stream>>>(
            spk4, fc2w, fc2b, mem5, out + (size_t)t * 2 * B_SZ,
            out + 3200 + (size_t)t * 2 * B_SZ);

        float* tmp;
        tmp = m1r; m1r = m1w; m1w = tmp;
        tmp = m2r; m2r = m2w; m2w = tmp;
        tmp = m3r; m3r = m3w; m3w = tmp;
    }
}